// Round 1
// baseline (12429.246 us; speedup 1.0000x reference)
//
#include <hip/hip_runtime.h>
#include <hip/hip_bf16.h>

typedef __attribute__((ext_vector_type(8))) short bf16x8;   // MFMA A/B frag (16B)
typedef __attribute__((ext_vector_type(4))) float f32x4;    // MFMA C/D frag
using bf16 = __hip_bfloat16;
typedef unsigned long long u64;

constexpr int BB = 64, TT = 256, DIN = 512, HH = 1024, DOUT = 512;
constexpr int PW = 1032;        // LDS W pitch (shorts): 2064B/row -> 16B aligned, bank stride 4 (2-way, free)
constexpr int HWORDS = 8192;    // one h half-array (lo or hi): 128 koct x 64 rows (u64)
constexpr int PARSTRIDE = 2 * HWORDS;   // u64 per parity (lo+hi)
constexpr int NPAR = 4;         // h ring-buffer depth

#define MFMA16(a, b, c) __builtin_amdgcn_mfma_f32_16x16x32_bf16((a), (b), (c), 0, 0, 0)
#define ALOAD(p)  __hip_atomic_load((p),  __ATOMIC_RELAXED, __HIP_MEMORY_SCOPE_AGENT)
#define ASTORE(p, v) __hip_atomic_store((p), (v), __ATOMIC_RELAXED, __HIP_MEMORY_SCOPE_AGENT)

union frag_u { u64 q[2]; bf16x8 f; };

__device__ __forceinline__ short f2b(float f) {
  __hip_bfloat16 h = __float2bfloat16(f);           // RNE
  return *reinterpret_cast<short*>(&h);
}
__device__ __forceinline__ u64 pack4(float4 v) {
  return (u64)(unsigned short)f2b(v.x) | ((u64)(unsigned short)f2b(v.y) << 16) |
         ((u64)(unsigned short)f2b(v.z) << 32) | ((u64)(unsigned short)f2b(v.w) << 48);
}

// gate math: z -> (h bf16 bits), updates c register
__device__ __forceinline__ unsigned short gates(const float zv[4], const float br[4],
                                                float scale, float& cr, bool first) {
  float zf = (zv[0] + br[0]) * scale;
  float zi = (zv[1] + br[1]) * scale;
  float zo = (zv[2] + br[2]) * scale;
  float zg = (zv[3] + br[3]) * scale;
  float f = 1.0f / (1.0f + __expf(-zf));
  float i = 1.0f / (1.0f + __expf(-zi));
  float o = 1.0f / (1.0f + __expf(-zo));
  float g = tanhf(zg);
  float cn = f * (first ? 0.0f : cr) + i * g;
  cr = cn;
  __hip_bfloat16 hv = __float2bfloat16(o * tanhf(cn));
  return *reinterpret_cast<unsigned short*>(&hv);
}

// ---------------- persistent kernel: 256 blocks x 512 threads ----------------
// Layer-split topology to cut the per-step device-scope h all-gather (the measured
// bottleneck: 256 readers x 256KB/step = 64MB/step through L3 at ~7.3TB/s):
//   blocks  0.. 63 : layer-0 pipeline, 16 h-cols each. LDS = W0 h-rows [512,1536).
//                    x-part of W0 lives in 8 register frags/wave. Reads h0 only.
//   blocks 64..127 : layer-1 pipeline, 16 h-cols each. LDS = W1 h1-rows [1024,2048).
//                    h0-half of W1 lives in 16 register frags/wave. Reads h0+h1.
//   blocks 128..255: x->bf16 conversion only, then exit.
// Traffic/step: 64x128KB + 64x256KB = 24MB (was 64MB); 1 serial global round per
// chain-link per step (was 2). Cross-wave z-reduce via ds_add_f32 into an 8KB zbuf
// (frees LDS for the 2x wider tile). h ring depth 4; L0 waits flagsB >= t-3 before
// overwriting h0(t-4) so layer-1 readers are provably done (3 steps of slack).
__global__ void __launch_bounds__(512, 1)
lstm_persist(const float* __restrict__ x,  const float* __restrict__ W0,
             const float* __restrict__ b0, const float* __restrict__ W1,
             const float* __restrict__ b1, const float* __restrict__ Wfc,
             const float* __restrict__ bfc,
             u64* __restrict__ xbu, int use_xb,
             u64* __restrict__ h0s, u64* __restrict__ h1s,
             unsigned* __restrict__ flagsC, unsigned* __restrict__ flagsA,
             unsigned* __restrict__ flagsB, float* __restrict__ out) {
  __shared__ unsigned short lw[64 * PW];     // 129.0 KB  one-layer W^T tile, 64 z-cols x 1024 k
  __shared__ float zbuf[64][67];             // 16.75 KB  cross-wave z accumulator (ds_add_f32)
  __shared__ unsigned short hs[64][16];      // 2 KB      h-tile staging

  const int tid  = threadIdx.x;
  const int wg   = blockIdx.x;
  const int lane = tid & 63;
  const int wv   = tid >> 6;          // wave id 0..7 = K-eighth
  const int n    = lane & 15;
  const int oct  = lane >> 4;
  const float S0 = 1.0f / sqrtf((float)(DIN + HH));
  const float S1 = 1.0f / sqrtf((float)(HH + HH));

  // ---- epoch 0: convert x -> bf16 split layout xb[t][koct 64][row 64]; block wg does t=wg ----
  if (use_xb) {
    const int t = wg;
    for (int u2 = tid; u2 < 64 * 64; u2 += 512) {
      const int row = u2 & 63, ko = u2 >> 6;
      const float* p = x + ((size_t)row * TT + t) * DIN + ko * 8;
      float4 A = *(const float4*)p, Bq = *(const float4*)(p + 4);
      u64* d = xbu + ((size_t)(t * 64 + ko) * 64 + row) * 2;
      ASTORE(d, pack4(A));
      ASTORE(d + 1, pack4(Bq));
    }
  }
  __syncthreads();                                  // pre-barrier drain covers all waves' stores
  if (tid < 64) __builtin_amdgcn_s_waitcnt(0);
  if (tid == 0) ASTORE(flagsC + wg, 1u);

  if (wg >= 128) return;                            // converter-only blocks exit

  const int role1 = (wg >= 64);                     // layer-1 pipeline?
  const int wgl   = role1 ? (wg - 64) : wg;         // pipeline-local block id 0..63
  const int wcol  = wgl * 16;                       // first owned h-col

  // zero the atomic z accumulator (ordered before first use by the barriers below)
  for (int u2 = tid; u2 < 64 * 67; u2 += 512) ((float*)zbuf)[u2] = 0.f;

  // per-thread gate state: row = tid&63, h-cols {hA, hA+8}
  const int grow = tid & 63, hA = tid >> 6, hB = hA + 8;
  const float* bsrc = role1 ? b1 : b0;
  float bA[4], bBv[4];
#pragma unroll
  for (int g = 0; g < 4; ++g) {
    bA[g]  = bsrc[g * HH + wcol + hA];
    bBv[g] = bsrc[g * HH + wcol + hB];
  }
  float cA = 0.f, cB = 0.f;
  const float myScale = role1 ? S1 : S0;

  // ---- stage LDS W tile: 1024 h-facing rows x 64 z-cols, fp32 -> bf16 transposed ----
  {
    const float* Wsrc = role1 ? W1 : W0;
    const int rbase = role1 ? 1024 : 512;           // L1: h1 rows of W1; L0: h0 rows of W0
    for (int u2 = tid; u2 < 1024 * 16; u2 += 512) {
      const int k = u2 >> 4, g = (u2 >> 2) & 3, c4 = u2 & 3;
      float4 q = *(const float4*)(Wsrc + (size_t)(rbase + k) * 4096 + g * HH + wcol + c4 * 4);
      const int zc = g * 16 + c4 * 4;
      lw[(zc + 0) * PW + k] = (unsigned short)f2b(q.x);
      lw[(zc + 1) * PW + k] = (unsigned short)f2b(q.y);
      lw[(zc + 2) * PW + k] = (unsigned short)f2b(q.z);
      lw[(zc + 3) * PW + k] = (unsigned short)f2b(q.w);
    }
  }

  // ---- register-resident W frags: L0 = x-part of W0 (8), L1 = h0-half of W1 (16) ----
  bf16x8 wreg[16];
  {
    const float* Wsrc = role1 ? W1 : W0;
#pragma unroll
    for (int i = 0; i < 16; ++i) {
      bf16x8 f;
      if (role1 || i < 8) {
        const int s = i >> 2, ct3 = i & 3;
        const int k0 = role1 ? (wv * 128 + s * 32 + oct * 8) : (wv * 64 + s * 32 + oct * 8);
        const int col = ct3 * HH + wcol + n;
#pragma unroll
        for (int j = 0; j < 8; ++j) f[j] = f2b(Wsrc[(size_t)(k0 + j) * 4096 + col]);
      } else {
#pragma unroll
        for (int j = 0; j < 8; ++j) f[j] = 0;
      }
      wreg[i] = f;
    }
  }
  __syncthreads();

  f32x4 acc[4][4];
  auto zclear = [&]() {
#pragma unroll
    for (int rt = 0; rt < 4; ++rt)
#pragma unroll
      for (int ct = 0; ct < 4; ++ct) acc[rt][ct] = (f32x4){0.f, 0.f, 0.f, 0.f};
  };
  auto hbase = [&](u64* arr, int t) -> const u64* {
    return arr + (size_t)(t & 3) * PARSTRIDE;
  };

  // z += h * W  (B from LDS tile)
  auto hgemm_lds = [&](const u64* hb) {
    u64 lo[16], hi[16];
#pragma unroll
    for (int i = 0; i < 16; ++i) {
      const int s = i >> 2, rt = i & 3;
      const int idx = (wv * 16 + s * 4 + oct) * 64 + rt * 16 + n;
      lo[i] = ALOAD(hb + idx);
      hi[i] = ALOAD(hb + HWORDS + idx);
    }
#pragma unroll
    for (int s = 0; s < 4; ++s) {
      const int kp = wv * 128 + s * 32 + oct * 8;
      bf16x8 bw0 = *(const bf16x8*)&lw[(0 * 16 + n) * PW + kp];
      bf16x8 bw1 = *(const bf16x8*)&lw[(1 * 16 + n) * PW + kp];
      bf16x8 bw2 = *(const bf16x8*)&lw[(2 * 16 + n) * PW + kp];
      bf16x8 bw3 = *(const bf16x8*)&lw[(3 * 16 + n) * PW + kp];
#pragma unroll
      for (int rt = 0; rt < 4; ++rt) {
        frag_u u; u.q[0] = lo[s * 4 + rt]; u.q[1] = hi[s * 4 + rt];
        acc[rt][0] = MFMA16(u.f, bw0, acc[rt][0]);
        acc[rt][1] = MFMA16(u.f, bw1, acc[rt][1]);
        acc[rt][2] = MFMA16(u.f, bw2, acc[rt][2]);
        acc[rt][3] = MFMA16(u.f, bw3, acc[rt][3]);
      }
    }
  };
  // z += h * W  (B from wreg, L1 h0-part)
  auto hgemm_reg = [&](const u64* hb) {
    u64 lo[16], hi[16];
#pragma unroll
    for (int i = 0; i < 16; ++i) {
      const int s = i >> 2, rt = i & 3;
      const int idx = (wv * 16 + s * 4 + oct) * 64 + rt * 16 + n;
      lo[i] = ALOAD(hb + idx);
      hi[i] = ALOAD(hb + HWORDS + idx);
    }
#pragma unroll
    for (int s = 0; s < 4; ++s)
#pragma unroll
      for (int rt = 0; rt < 4; ++rt) {
        frag_u u; u.q[0] = lo[s * 4 + rt]; u.q[1] = hi[s * 4 + rt];
        acc[rt][0] = MFMA16(u.f, wreg[s * 4 + 0], acc[rt][0]);
        acc[rt][1] = MFMA16(u.f, wreg[s * 4 + 1], acc[rt][1]);
        acc[rt][2] = MFMA16(u.f, wreg[s * 4 + 2], acc[rt][2]);
        acc[rt][3] = MFMA16(u.f, wreg[s * 4 + 3], acc[rt][3]);
      }
  };
  // z0 += x(t) * W0x (B from wreg[0..8))
  auto xpart = [&](int t) {
    if (use_xb) {
      const bf16* xb = (const bf16*)xbu;
#pragma unroll
      for (int s = 0; s < 2; ++s) {
        const int ko = wv * 8 + s * 4 + oct;
#pragma unroll
        for (int rt = 0; rt < 4; ++rt) {
          bf16x8 a = *(const bf16x8*)(xb + ((size_t)(t * 64 + ko) * 64 + rt * 16 + n) * 8);
          acc[rt][0] = MFMA16(a, wreg[s * 4 + 0], acc[rt][0]);
          acc[rt][1] = MFMA16(a, wreg[s * 4 + 1], acc[rt][1]);
          acc[rt][2] = MFMA16(a, wreg[s * 4 + 2], acc[rt][2]);
          acc[rt][3] = MFMA16(a, wreg[s * 4 + 3], acc[rt][3]);
        }
      }
    } else {
#pragma unroll
      for (int s = 0; s < 2; ++s) {
        const int kp = wv * 64 + s * 32 + oct * 8;
#pragma unroll
        for (int rt = 0; rt < 4; ++rt) {
          const float* p = x + ((size_t)(rt * 16 + n) * TT + t) * DIN + kp;
          float4 A = *(const float4*)p, Bq = *(const float4*)(p + 4);
          bf16x8 a;
          a[0] = f2b(A.x); a[1] = f2b(A.y); a[2] = f2b(A.z); a[3] = f2b(A.w);
          a[4] = f2b(Bq.x); a[5] = f2b(Bq.y); a[6] = f2b(Bq.z); a[7] = f2b(Bq.w);
          acc[rt][0] = MFMA16(a, wreg[s * 4 + 0], acc[rt][0]);
          acc[rt][1] = MFMA16(a, wreg[s * 4 + 1], acc[rt][1]);
          acc[rt][2] = MFMA16(a, wreg[s * 4 + 2], acc[rt][2]);
          acc[rt][3] = MFMA16(a, wreg[s * 4 + 3], acc[rt][3]);
        }
      }
    }
  };
  // cross-wave reduce: 8 waves ds_add the full 64x64 z tile
  auto zreduce = [&]() {
#pragma unroll
    for (int rt = 0; rt < 4; ++rt)
#pragma unroll
      for (int ct = 0; ct < 4; ++ct)
#pragma unroll
        for (int r = 0; r < 4; ++r)
          atomicAdd(&zbuf[rt * 16 + oct * 4 + r][ct * 16 + n], acc[rt][ct][r]);
  };
  // gates for this thread's 2 h-values; reads + re-zeroes its own 8 zbuf slots
  auto gates_phase = [&](bool first) {
    float zA[4], zB[4];
#pragma unroll
    for (int g = 0; g < 4; ++g) { zA[g] = zbuf[grow][g * 16 + hA]; zB[g] = zbuf[grow][g * 16 + hB]; }
#pragma unroll
    for (int g = 0; g < 4; ++g) { zbuf[grow][g * 16 + hA] = 0.f; zbuf[grow][g * 16 + hB] = 0.f; }
    hs[grow][hA] = gates(zA, bA, myScale, cA, first);
    hs[grow][hB] = gates(zB, bBv, myScale, cB, first);
  };
  // wave0: write 64x16 h-tile (2 koct, lo+hi) + release flag
  auto publish = [&](u64* harr, int par, unsigned* flag, unsigned val) {
    if (tid < 64) {
      const u64* hrow = (const u64*)&hs[lane][0];
      u64 w0 = hrow[0], w1 = hrow[1], w2 = hrow[2], w3 = hrow[3];
      u64* base = harr + (size_t)par * PARSTRIDE;
      const int kb = wcol >> 3;                     // koct base = 2*wgl
      ASTORE(base + (size_t)(kb + 0) * 64 + lane, w0);           // ko0 lo
      ASTORE(base + HWORDS + (size_t)(kb + 0) * 64 + lane, w1);  // ko0 hi
      ASTORE(base + (size_t)(kb + 1) * 64 + lane, w2);           // ko1 lo
      ASTORE(base + HWORDS + (size_t)(kb + 1) * 64 + lane, w3);  // ko1 hi
      __builtin_amdgcn_s_waitcnt(0);
    }
    if (tid == 0) ASTORE(flag + wgl, val);
  };
  auto bar1 = [&](const unsigned* fa, unsigned ta) {
    if (tid < 64) {
      for (;;) {
        unsigned a = ALOAD(fa + lane);
        if (__all((int)(a >= ta))) break;
        __builtin_amdgcn_s_sleep(1);
      }
    }
    __syncthreads();
    __builtin_amdgcn_fence(__ATOMIC_ACQUIRE, "workgroup");
  };
  auto bar2 = [&](const unsigned* fa, unsigned ta, const unsigned* fb2, unsigned tb2) {
    if (tid < 64) {
      for (;;) {
        unsigned a = ALOAD(fa + lane);
        unsigned b = ALOAD(fb2 + lane);
        if (__all((int)(a >= ta && b >= tb2))) break;
        __builtin_amdgcn_s_sleep(1);
      }
    }
    __syncthreads();
    __builtin_amdgcn_fence(__ATOMIC_ACQUIRE, "workgroup");
  };

  if (!role1) {
    // ================= layer-0 pipeline =================
    // wait x conversion (all 256 blocks)
    if (tid < 64) {
      const u64* p = (const u64*)(flagsC + tid * 4);
      for (;;) {
        u64 a = ALOAD(p), b = ALOAD(p + 1);
        if ((unsigned)a && (unsigned)(a >> 32) && (unsigned)b && (unsigned)(b >> 32)) break;
        __builtin_amdgcn_s_sleep(1);
      }
    }
    __syncthreads();
    __builtin_amdgcn_fence(__ATOMIC_ACQUIRE, "workgroup");

    zclear();
    xpart(0);
    zreduce(); __syncthreads();
    gates_phase(true); __syncthreads();
    publish(h0s, 0, flagsA, 1u);                    // h0(0)
    zclear(); xpart(1);

    for (int t = 1; t < TT; ++t) {
      // flagsA>=t : h0(t-1) visible. flagsB>=t-3 : L1 done reading h0(t-4) (our overwrite target).
      bar2(flagsA, (unsigned)t, flagsB, t > 3 ? (unsigned)(t - 3) : 0u);
      hgemm_lds(hbase(h0s, t - 1));                 // z0 += h0(t-1) * W0h
      zreduce(); __syncthreads();
      gates_phase(false); __syncthreads();
      publish(h0s, t & 3, flagsA, (unsigned)t + 1u);
      if (t < TT - 1) { zclear(); xpart(t + 1); }   // overlap next x-part
    }

    // ============ final FC: out = h1(255) @ Wfc + bfc (L0 blocks 0..31) ============
    if (wg < 32) {
      bar1(flagsB, 256u);                           // h1(255) visible
      for (int u2 = tid; u2 < 1024 * 4; u2 += 512) {
        const int k = u2 >> 2, c4 = u2 & 3;
        float4 q = *(const float4*)(Wfc + (size_t)k * DOUT + wg * 16 + c4 * 4);
        lw[(c4 * 4 + 0) * PW + k] = (unsigned short)f2b(q.x);
        lw[(c4 * 4 + 1) * PW + k] = (unsigned short)f2b(q.y);
        lw[(c4 * 4 + 2) * PW + k] = (unsigned short)f2b(q.z);
        lw[(c4 * 4 + 3) * PW + k] = (unsigned short)f2b(q.w);
      }
      __syncthreads();
      if (tid < 256) {
        const int v4 = tid >> 6;
        const u64* hbp = h1s + (size_t)(255 & 3) * PARSTRIDE;  // h1(255), parity 3
        f32x4 acc0 = {0.f, 0.f, 0.f, 0.f}, acc1 = {0.f, 0.f, 0.f, 0.f};
#pragma unroll
        for (int it = 0; it < 16; ++it) {
          const int idxA = (it * 8 + oct) * 64 + v4 * 16 + n;
          const int idxB = (it * 8 + 4 + oct) * 64 + v4 * 16 + n;
          frag_u uA, uB;
          uA.q[0] = ALOAD(hbp + idxA); uA.q[1] = ALOAD(hbp + HWORDS + idxA);
          uB.q[0] = ALOAD(hbp + idxB); uB.q[1] = ALOAD(hbp + HWORDS + idxB);
          bf16x8 bwA = *(const bf16x8*)&lw[n * PW + it * 64 + oct * 8];
          bf16x8 bwB = *(const bf16x8*)&lw[n * PW + it * 64 + 32 + oct * 8];
          acc0 = MFMA16(uA.f, bwA, acc0);
          acc1 = MFMA16(uB.f, bwB, acc1);
        }
        float bb = bfc[wg * 16 + n];
#pragma unroll
        for (int r = 0; r < 4; ++r) {
          const int row = v4 * 16 + oct * 4 + r;
          out[(size_t)row * DOUT + wg * 16 + n] = acc0[r] + acc1[r] + bb;
        }
      }
    }
  } else {
    // ================= layer-1 pipeline (lags L0 by >=1 step) =================
    bar1(flagsA, 1u);                               // h0(0) visible
    zclear();
    hgemm_reg(hbase(h0s, 0));                       // z1 += h0(0) * W1[0:1024] (regs)
    for (int s2 = 0; s2 < TT; ++s2) {
      if (s2 > 0) {
        bar1(flagsB, (unsigned)s2);                 // h1(s2-1) visible (own-chain critical wait)
        hgemm_lds(hbase(h1s, s2 - 1));              // z1 += h1(s2-1) * W1[1024:2048] (LDS)
      }
      zreduce(); __syncthreads();
      gates_phase(s2 == 0); __syncthreads();
      publish(h1s, s2 & 3, flagsB, (unsigned)s2 + 1u);
      if (s2 < TT - 1) {
        bar1(flagsA, (unsigned)s2 + 2u);            // h0(s2+1) visible (usually already set)
        zclear();
        hgemm_reg(hbase(h0s, s2 + 1));              // prefetch next h0-part off the h1 chain
      }
    }
  }
}

extern "C" void kernel_launch(void* const* d_in, const int* in_sizes, int n_in,
                              void* d_out, int out_size, void* d_ws, size_t ws_size,
                              hipStream_t stream) {
  const float* x   = (const float*)d_in[0];
  const float* W0  = (const float*)d_in[1];
  const float* b0  = (const float*)d_in[2];
  const float* W1  = (const float*)d_in[3];
  const float* b1  = (const float*)d_in[4];
  const float* Wfc = (const float*)d_in[5];
  const float* bfc = (const float*)d_in[6];

  // ---- workspace: flags (4KB) + h rings (1MB) + xb (16.78MB) ----
  char* ws = (char*)d_ws;
  unsigned* flagsC = (unsigned*)ws;                   // 256 u32 (conversion epoch)
  unsigned* flagsA = (unsigned*)(ws + 1024);          // 64 u32 (h0 chain)
  unsigned* flagsB = (unsigned*)(ws + 2048);          // 64 u32 (h1 chain)
  u64* h0s = (u64*)(ws + 4096);                       // NPAR * 2*HWORDS u64 = 512 KB
  u64* h1s = h0s + (size_t)NPAR * PARSTRIDE;          // 512 KB
  u64* xbu = h1s + (size_t)NPAR * PARSTRIDE;          // 256*64*64 * 16B = 16.78 MB
  size_t needed = 4096 + 2 * (size_t)NPAR * PARSTRIDE * 8 + (size_t)TT * 64 * 64 * 16;
  int use_xb = (ws_size >= needed) ? 1 : 0;

  hipMemsetAsync(ws, 0, 4096, stream);                // zero all flag arrays

  lstm_persist<<<dim3(256), dim3(512), 0, stream>>>(
      x, W0, b0, W1, b1, Wfc, bfc, xbu, use_xb, h0s, h1s,
      flagsC, flagsA, flagsB, (float*)d_out);
}

// Round 2
// 12356.374 us; speedup vs baseline: 1.0059x; 1.0059x over previous
//
#include <hip/hip_runtime.h>
#include <hip/hip_bf16.h>

typedef __attribute__((ext_vector_type(8))) short bf16x8;   // MFMA A/B frag (16B)
typedef __attribute__((ext_vector_type(4))) float f32x4;    // MFMA C/D frag
using bf16 = __hip_bfloat16;
typedef unsigned long long u64;

constexpr int BB = 64, TT = 256, DIN = 512, HH = 1024, DOUT = 512;
constexpr int PW = 1032;        // LDS W pitch (shorts)
constexpr int HWORDS = 8192;    // one h half-array (lo or hi): 128 koct x 64 rows (u64)
constexpr int PARSTRIDE = 2 * HWORDS;   // u64 per parity (lo+hi)
constexpr int NPAR = 4;         // h ring-buffer depth

#define MFMA16(a, b, c) __builtin_amdgcn_mfma_f32_16x16x32_bf16((a), (b), (c), 0, 0, 0)
#define ALOAD(p)  __hip_atomic_load((p),  __ATOMIC_RELAXED, __HIP_MEMORY_SCOPE_AGENT)
#define ASTORE(p, v) __hip_atomic_store((p), (v), __ATOMIC_RELAXED, __HIP_MEMORY_SCOPE_AGENT)

union frag_u { u64 q[2]; bf16x8 f; };

__device__ __forceinline__ short f2b(float f) {
  __hip_bfloat16 h = __float2bfloat16(f);           // RNE
  return *reinterpret_cast<short*>(&h);
}
__device__ __forceinline__ u64 pack4(float4 v) {
  return (u64)(unsigned short)f2b(v.x) | ((u64)(unsigned short)f2b(v.y) << 16) |
         ((u64)(unsigned short)f2b(v.z) << 32) | ((u64)(unsigned short)f2b(v.w) << 48);
}

__device__ __forceinline__ unsigned short gates(const float zv[4], const float br[4],
                                                float scale, float& cr, bool first) {
  float zf = (zv[0] + br[0]) * scale;
  float zi = (zv[1] + br[1]) * scale;
  float zo = (zv[2] + br[2]) * scale;
  float zg = (zv[3] + br[3]) * scale;
  float f = 1.0f / (1.0f + __expf(-zf));
  float i = 1.0f / (1.0f + __expf(-zi));
  float o = 1.0f / (1.0f + __expf(-zo));
  float g = tanhf(zg);
  float cn = f * (first ? 0.0f : cr) + i * g;
  cr = cn;
  __hip_bfloat16 hv = __float2bfloat16(o * tanhf(cn));
  return *reinterpret_cast<unsigned short*>(&hv);
}

// ---------------- persistent kernel: 256 blocks x 512 threads ----------------
// Layer-split topology (round-1) with the register fix: NO register-resident W.
// Round-1's wreg[16] (64 always-live VGPRs) + acc (64) + lo/hi (64) demanded ~190
// VGPRs; compiler allocated 128 -> scratch spill/remat in the steady loop (~8.6GB
// of latency-bound private traffic) = the 12ms disaster. Now the non-LDS half of W
// is pre-packed ONCE into workspace in exact MFMA fragment order (per block, per
// wave, per frag, per lane, 16B units) and re-read each step as coalesced cached
// loads (block slice 64-128KB -> L2-resident on own XCD). Peak regs ~120.
//   blocks  0.. 63 : layer-0. LDS = W0 h-rows [512,1536). W0 x-part from wp0.
//   blocks 64..127 : layer-1. LDS = W1 h1-rows [1024,2048). W1 h0-part from wp1.
//   blocks 128..255: x->bf16 conversion only, then exit.
__global__ void __launch_bounds__(512, 2)
lstm_persist(const float* __restrict__ x,  const float* __restrict__ W0,
             const float* __restrict__ b0, const float* __restrict__ W1,
             const float* __restrict__ b1, const float* __restrict__ Wfc,
             const float* __restrict__ bfc,
             u64* __restrict__ xbu, int use_xb,
             u64* __restrict__ wp0, u64* __restrict__ wp1, int use_wp,
             u64* __restrict__ h0s, u64* __restrict__ h1s,
             unsigned* __restrict__ flagsC, unsigned* __restrict__ flagsA,
             unsigned* __restrict__ flagsB, float* __restrict__ out) {
  __shared__ unsigned short lw[64 * PW];     // 129.0 KB  one-layer W^T tile, 64 z-cols x 1024 k
  __shared__ float zbuf[64][67];             // 16.75 KB  cross-wave z accumulator (ds_add_f32)
  __shared__ unsigned short hs[64][16];      // 2 KB      h-tile staging

  const int tid  = threadIdx.x;
  const int wg   = blockIdx.x;
  const int lane = tid & 63;
  const int wv   = tid >> 6;          // wave id 0..7 = K-eighth
  const int n    = lane & 15;
  const int oct  = lane >> 4;
  const float S0 = 1.0f / sqrtf((float)(DIN + HH));
  const float S1 = 1.0f / sqrtf((float)(HH + HH));

  // ---- epoch 0: convert x -> bf16 split layout xb[t][koct 64][row 64]; block wg does t=wg ----
  if (use_xb) {
    const int t = wg;
    for (int u2 = tid; u2 < 64 * 64; u2 += 512) {
      const int row = u2 & 63, ko = u2 >> 6;
      const float* p = x + ((size_t)row * TT + t) * DIN + ko * 8;
      float4 A = *(const float4*)p, Bq = *(const float4*)(p + 4);
      u64* d = xbu + ((size_t)(t * 64 + ko) * 64 + row) * 2;
      ASTORE(d, pack4(A));
      ASTORE(d + 1, pack4(Bq));
    }
  }

  const int role1 = (wg >= 64) && (wg < 128);
  const int wgl   = (wg < 128) ? (role1 ? (wg - 64) : wg) : 0;
  const int wcol  = wgl * 16;

  // ---- epoch 0b (worker blocks): pack own W slice into fragment order ----
  // dst unit u = ((wv*NF + f)*64 + lane), 16B = 8 consecutive k, f = s*4+ct.
  if (use_wp && wg < 128) {
    const float* Wsrc = role1 ? W1 : W0;
    u64* myp = role1 ? (wp1 + (size_t)wgl * 8 * 16 * 64 * 2)
                     : (wp0 + (size_t)wgl * 8 * 8 * 64 * 2);
    const int NF = role1 ? 16 : 8;              // frags per wave
    const int KW = role1 ? 128 : 64;            // K per wave
    const int NU = 8 * NF * 64;                 // units per block
    for (int u2 = tid; u2 < NU; u2 += 512) {
      const int lane2 = u2 & 63;
      const int f = (u2 >> 6) & (NF - 1);
      const int wv2 = u2 >> (role1 ? 10 : 9);
      const int s = f >> 2, ct = f & 3;
      const int k0 = wv2 * KW + s * 32 + ((lane2 >> 4) << 3);
      const int col = ct * HH + wcol + (lane2 & 15);
      u64 q0 = 0, q1 = 0;
#pragma unroll
      for (int j = 0; j < 4; ++j)
        q0 |= (u64)(unsigned short)f2b(Wsrc[(size_t)(k0 + j) * 4096 + col]) << (16 * j);
#pragma unroll
      for (int j = 0; j < 4; ++j)
        q1 |= (u64)(unsigned short)f2b(Wsrc[(size_t)(k0 + 4 + j) * 4096 + col]) << (16 * j);
      u64* d = myp + (size_t)u2 * 2;
      d[0] = q0; d[1] = q1;
    }
  }
  __syncthreads();
  if (tid < 64) __builtin_amdgcn_s_waitcnt(0);
  if (tid == 0) ASTORE(flagsC + wg, 1u);

  if (wg >= 128) return;                        // converter-only blocks exit

  // per-wave packed-W fragment base (plain cached loads; own-block data)
  const u64* wpw = role1
      ? wp1 + ((size_t)wgl * 8 * 16 + (size_t)wv * 16) * 64 * 2
      : wp0 + ((size_t)wgl * 8 * 8  + (size_t)wv * 8 ) * 64 * 2;

  // zero the atomic z accumulator
  for (int u2 = tid; u2 < 64 * 67; u2 += 512) ((float*)zbuf)[u2] = 0.f;

  // per-thread gate state: row = tid&63, h-cols {hA, hA+8}
  const int grow = tid & 63, hA = tid >> 6, hB = hA + 8;
  const float* bsrc = role1 ? b1 : b0;
  float bA[4], bBv[4];
#pragma unroll
  for (int g = 0; g < 4; ++g) {
    bA[g]  = bsrc[g * HH + wcol + hA];
    bBv[g] = bsrc[g * HH + wcol + hB];
  }
  float cA = 0.f, cB = 0.f;
  const float myScale = role1 ? S1 : S0;

  // ---- stage LDS W tile: 1024 h-facing rows x 64 z-cols, fp32 -> bf16 transposed ----
  {
    const float* Wsrc = role1 ? W1 : W0;
    const int rbase = role1 ? 1024 : 512;
    for (int u2 = tid; u2 < 1024 * 16; u2 += 512) {
      const int k = u2 >> 4, g = (u2 >> 2) & 3, c4 = u2 & 3;
      float4 q = *(const float4*)(Wsrc + (size_t)(rbase + k) * 4096 + g * HH + wcol + c4 * 4);
      const int zc = g * 16 + c4 * 4;
      lw[(zc + 0) * PW + k] = (unsigned short)f2b(q.x);
      lw[(zc + 1) * PW + k] = (unsigned short)f2b(q.y);
      lw[(zc + 2) * PW + k] = (unsigned short)f2b(q.z);
      lw[(zc + 3) * PW + k] = (unsigned short)f2b(q.w);
    }
  }
  __syncthreads();

  f32x4 acc[4][4];
  auto zclear = [&]() {
#pragma unroll
    for (int rt = 0; rt < 4; ++rt)
#pragma unroll
      for (int ct = 0; ct < 4; ++ct) acc[rt][ct] = (f32x4){0.f, 0.f, 0.f, 0.f};
  };
  auto hbase = [&](u64* arr, int t) -> const u64* {
    return arr + (size_t)(t & 3) * PARSTRIDE;
  };
  // fallback scalar W gather (only when workspace too small for wp)
  auto gatherW = [&](const float* Wsrc, int k0, int col) -> bf16x8 {
    bf16x8 f;
#pragma unroll
    for (int j = 0; j < 8; ++j) f[j] = f2b(Wsrc[(size_t)(k0 + j) * 4096 + col]);
    return f;
  };

  // z += h * W  (B from LDS tile)
  auto hgemm_lds = [&](const u64* hb) {
    u64 lo[16], hi[16];
#pragma unroll
    for (int i = 0; i < 16; ++i) {
      const int s = i >> 2, rt = i & 3;
      const int idx = (wv * 16 + s * 4 + oct) * 64 + rt * 16 + n;
      lo[i] = ALOAD(hb + idx);
      hi[i] = ALOAD(hb + HWORDS + idx);
    }
#pragma unroll
    for (int s = 0; s < 4; ++s) {
      const int kp = wv * 128 + s * 32 + oct * 8;
      bf16x8 bw0 = *(const bf16x8*)&lw[(0 * 16 + n) * PW + kp];
      bf16x8 bw1 = *(const bf16x8*)&lw[(1 * 16 + n) * PW + kp];
      bf16x8 bw2 = *(const bf16x8*)&lw[(2 * 16 + n) * PW + kp];
      bf16x8 bw3 = *(const bf16x8*)&lw[(3 * 16 + n) * PW + kp];
#pragma unroll
      for (int rt = 0; rt < 4; ++rt) {
        frag_u u; u.q[0] = lo[s * 4 + rt]; u.q[1] = hi[s * 4 + rt];
        acc[rt][0] = MFMA16(u.f, bw0, acc[rt][0]);
        acc[rt][1] = MFMA16(u.f, bw1, acc[rt][1]);
        acc[rt][2] = MFMA16(u.f, bw2, acc[rt][2]);
        acc[rt][3] = MFMA16(u.f, bw3, acc[rt][3]);
      }
    }
  };
  // z += h * W  (B from packed-global frags; L1 h0-part, K=128/wave)
  auto hgemm_glb = [&](const u64* hb) {
    u64 lo[16], hi[16];
#pragma unroll
    for (int i = 0; i < 16; ++i) {
      const int s = i >> 2, rt = i & 3;
      const int idx = (wv * 16 + s * 4 + oct) * 64 + rt * 16 + n;
      lo[i] = ALOAD(hb + idx);
      hi[i] = ALOAD(hb + HWORDS + idx);
    }
#pragma unroll
    for (int s = 0; s < 4; ++s) {
      bf16x8 bw0, bw1, bw2, bw3;
      if (use_wp) {
        bw0 = *(const bf16x8*)(wpw + (size_t)((s * 4 + 0) * 64 + lane) * 2);
        bw1 = *(const bf16x8*)(wpw + (size_t)((s * 4 + 1) * 64 + lane) * 2);
        bw2 = *(const bf16x8*)(wpw + (size_t)((s * 4 + 2) * 64 + lane) * 2);
        bw3 = *(const bf16x8*)(wpw + (size_t)((s * 4 + 3) * 64 + lane) * 2);
      } else {
        const int k0 = wv * 128 + s * 32 + oct * 8;
        bw0 = gatherW(W1, k0, 0 * HH + wcol + n);
        bw1 = gatherW(W1, k0, 1 * HH + wcol + n);
        bw2 = gatherW(W1, k0, 2 * HH + wcol + n);
        bw3 = gatherW(W1, k0, 3 * HH + wcol + n);
      }
#pragma unroll
      for (int rt = 0; rt < 4; ++rt) {
        frag_u u; u.q[0] = lo[s * 4 + rt]; u.q[1] = hi[s * 4 + rt];
        acc[rt][0] = MFMA16(u.f, bw0, acc[rt][0]);
        acc[rt][1] = MFMA16(u.f, bw1, acc[rt][1]);
        acc[rt][2] = MFMA16(u.f, bw2, acc[rt][2]);
        acc[rt][3] = MFMA16(u.f, bw3, acc[rt][3]);
      }
    }
  };
  // z0 += x(t) * W0x (B from packed-global frags, K=64/wave)
  auto xpart = [&](int t) {
#pragma unroll
    for (int s = 0; s < 2; ++s) {
      bf16x8 bw0, bw1, bw2, bw3;
      if (use_wp) {
        bw0 = *(const bf16x8*)(wpw + (size_t)((s * 4 + 0) * 64 + lane) * 2);
        bw1 = *(const bf16x8*)(wpw + (size_t)((s * 4 + 1) * 64 + lane) * 2);
        bw2 = *(const bf16x8*)(wpw + (size_t)((s * 4 + 2) * 64 + lane) * 2);
        bw3 = *(const bf16x8*)(wpw + (size_t)((s * 4 + 3) * 64 + lane) * 2);
      } else {
        const int k0 = wv * 64 + s * 32 + oct * 8;
        bw0 = gatherW(W0, k0, 0 * HH + wcol + n);
        bw1 = gatherW(W0, k0, 1 * HH + wcol + n);
        bw2 = gatherW(W0, k0, 2 * HH + wcol + n);
        bw3 = gatherW(W0, k0, 3 * HH + wcol + n);
      }
      if (use_xb) {
        const bf16* xb = (const bf16*)xbu;
        const int ko = wv * 8 + s * 4 + oct;
#pragma unroll
        for (int rt = 0; rt < 4; ++rt) {
          bf16x8 a = *(const bf16x8*)(xb + ((size_t)(t * 64 + ko) * 64 + rt * 16 + n) * 8);
          acc[rt][0] = MFMA16(a, bw0, acc[rt][0]);
          acc[rt][1] = MFMA16(a, bw1, acc[rt][1]);
          acc[rt][2] = MFMA16(a, bw2, acc[rt][2]);
          acc[rt][3] = MFMA16(a, bw3, acc[rt][3]);
        }
      } else {
        const int kp = wv * 64 + s * 32 + oct * 8;
#pragma unroll
        for (int rt = 0; rt < 4; ++rt) {
          const float* p = x + ((size_t)(rt * 16 + n) * TT + t) * DIN + kp;
          float4 A = *(const float4*)p, Bq = *(const float4*)(p + 4);
          bf16x8 a;
          a[0] = f2b(A.x); a[1] = f2b(A.y); a[2] = f2b(A.z); a[3] = f2b(A.w);
          a[4] = f2b(Bq.x); a[5] = f2b(Bq.y); a[6] = f2b(Bq.z); a[7] = f2b(Bq.w);
          acc[rt][0] = MFMA16(a, bw0, acc[rt][0]);
          acc[rt][1] = MFMA16(a, bw1, acc[rt][1]);
          acc[rt][2] = MFMA16(a, bw2, acc[rt][2]);
          acc[rt][3] = MFMA16(a, bw3, acc[rt][3]);
        }
      }
    }
  };
  // cross-wave reduce: 8 waves ds_add the full 64x64 z tile
  auto zreduce = [&]() {
#pragma unroll
    for (int rt = 0; rt < 4; ++rt)
#pragma unroll
      for (int ct = 0; ct < 4; ++ct)
#pragma unroll
        for (int r = 0; r < 4; ++r)
          atomicAdd(&zbuf[rt * 16 + oct * 4 + r][ct * 16 + n], acc[rt][ct][r]);
  };
  auto gates_phase = [&](bool first) {
    float zA[4], zB[4];
#pragma unroll
    for (int g = 0; g < 4; ++g) { zA[g] = zbuf[grow][g * 16 + hA]; zB[g] = zbuf[grow][g * 16 + hB]; }
#pragma unroll
    for (int g = 0; g < 4; ++g) { zbuf[grow][g * 16 + hA] = 0.f; zbuf[grow][g * 16 + hB] = 0.f; }
    hs[grow][hA] = gates(zA, bA, myScale, cA, first);
    hs[grow][hB] = gates(zB, bBv, myScale, cB, first);
  };
  // wave0: write 64x16 h-tile (2 koct, lo+hi) + release flag
  auto publish = [&](u64* harr, int par, unsigned* flag, unsigned val) {
    if (tid < 64) {
      const u64* hrow = (const u64*)&hs[lane][0];
      u64 w0 = hrow[0], w1 = hrow[1], w2 = hrow[2], w3 = hrow[3];
      u64* base = harr + (size_t)par * PARSTRIDE;
      const int kb = wcol >> 3;                     // koct base = 2*wgl
      ASTORE(base + (size_t)(kb + 0) * 64 + lane, w0);
      ASTORE(base + HWORDS + (size_t)(kb + 0) * 64 + lane, w1);
      ASTORE(base + (size_t)(kb + 1) * 64 + lane, w2);
      ASTORE(base + HWORDS + (size_t)(kb + 1) * 64 + lane, w3);
      __builtin_amdgcn_s_waitcnt(0);
    }
    if (tid == 0) ASTORE(flag + wgl, val);
  };
  auto bar1 = [&](const unsigned* fa, unsigned ta) {
    if (tid < 64) {
      for (;;) {
        unsigned a = ALOAD(fa + lane);
        if (__all((int)(a >= ta))) break;
        __builtin_amdgcn_s_sleep(1);
      }
    }
    __syncthreads();
    __builtin_amdgcn_fence(__ATOMIC_ACQUIRE, "workgroup");
  };
  auto bar2 = [&](const unsigned* fa, unsigned ta, const unsigned* fb2, unsigned tb2) {
    if (tid < 64) {
      for (;;) {
        unsigned a = ALOAD(fa + lane);
        unsigned b = ALOAD(fb2 + lane);
        if (__all((int)(a >= ta && b >= tb2))) break;
        __builtin_amdgcn_s_sleep(1);
      }
    }
    __syncthreads();
    __builtin_amdgcn_fence(__ATOMIC_ACQUIRE, "workgroup");
  };

  if (!role1) {
    // ================= layer-0 pipeline =================
    if (tid < 64) {                                 // wait x conversion (all 256 blocks)
      const u64* p = (const u64*)(flagsC + tid * 4);
      for (;;) {
        u64 a = ALOAD(p), b = ALOAD(p + 1);
        if ((unsigned)a && (unsigned)(a >> 32) && (unsigned)b && (unsigned)(b >> 32)) break;
        __builtin_amdgcn_s_sleep(1);
      }
    }
    __syncthreads();
    __builtin_amdgcn_fence(__ATOMIC_ACQUIRE, "workgroup");

    zclear();
    xpart(0);
    zreduce(); __syncthreads();
    gates_phase(true); __syncthreads();
    publish(h0s, 0, flagsA, 1u);                    // h0(0)
    zclear(); xpart(1);

    for (int t = 1; t < TT; ++t) {
      // flagsA>=t : h0(t-1) visible. flagsB>=t-3 : L1 done reading h0(t-4) (our overwrite target).
      bar2(flagsA, (unsigned)t, flagsB, t > 3 ? (unsigned)(t - 3) : 0u);
      hgemm_lds(hbase(h0s, t - 1));                 // z0 += h0(t-1) * W0h
      zreduce(); __syncthreads();
      gates_phase(false); __syncthreads();
      publish(h0s, t & 3, flagsA, (unsigned)t + 1u);
      if (t < TT - 1) { zclear(); xpart(t + 1); }   // overlap next x-part
    }

    // ============ final FC: out = h1(255) @ Wfc + bfc (L0 blocks 0..31) ============
    if (wg < 32) {
      bar1(flagsB, 256u);                           // h1(255) visible
      for (int u2 = tid; u2 < 1024 * 4; u2 += 512) {
        const int k = u2 >> 2, c4 = u2 & 3;
        float4 q = *(const float4*)(Wfc + (size_t)k * DOUT + wg * 16 + c4 * 4);
        lw[(c4 * 4 + 0) * PW + k] = (unsigned short)f2b(q.x);
        lw[(c4 * 4 + 1) * PW + k] = (unsigned short)f2b(q.y);
        lw[(c4 * 4 + 2) * PW + k] = (unsigned short)f2b(q.z);
        lw[(c4 * 4 + 3) * PW + k] = (unsigned short)f2b(q.w);
      }
      __syncthreads();
      if (tid < 256) {
        const int v4 = tid >> 6;
        const u64* hbp = h1s + (size_t)(255 & 3) * PARSTRIDE;  // h1(255), parity 3
        f32x4 acc0 = {0.f, 0.f, 0.f, 0.f}, acc1 = {0.f, 0.f, 0.f, 0.f};
#pragma unroll
        for (int it = 0; it < 16; ++it) {
          const int idxA = (it * 8 + oct) * 64 + v4 * 16 + n;
          const int idxB = (it * 8 + 4 + oct) * 64 + v4 * 16 + n;
          frag_u uA, uB;
          uA.q[0] = ALOAD(hbp + idxA); uA.q[1] = ALOAD(hbp + HWORDS + idxA);
          uB.q[0] = ALOAD(hbp + idxB); uB.q[1] = ALOAD(hbp + HWORDS + idxB);
          bf16x8 bwA = *(const bf16x8*)&lw[n * PW + it * 64 + oct * 8];
          bf16x8 bwB = *(const bf16x8*)&lw[n * PW + it * 64 + 32 + oct * 8];
          acc0 = MFMA16(uA.f, bwA, acc0);
          acc1 = MFMA16(uB.f, bwB, acc1);
        }
        float bb = bfc[wg * 16 + n];
#pragma unroll
        for (int r = 0; r < 4; ++r) {
          const int row = v4 * 16 + oct * 4 + r;
          out[(size_t)row * DOUT + wg * 16 + n] = acc0[r] + acc1[r] + bb;
        }
      }
    }
  } else {
    // ================= layer-1 pipeline (lags L0 by >=1 step) =================
    bar1(flagsA, 1u);                               // h0(0) visible
    zclear();
    hgemm_glb(hbase(h0s, 0));                       // z1 += h0(0) * W1[0:1024]
    for (int s2 = 0; s2 < TT; ++s2) {
      if (s2 > 0) {
        bar1(flagsB, (unsigned)s2);                 // h1(s2-1) visible (own-chain critical wait)
        hgemm_lds(hbase(h1s, s2 - 1));              // z1 += h1(s2-1) * W1[1024:2048] (LDS)
      }
      zreduce(); __syncthreads();
      gates_phase(s2 == 0); __syncthreads();
      publish(h1s, s2 & 3, flagsB, (unsigned)s2 + 1u);
      if (s2 < TT - 1) {
        bar1(flagsA, (unsigned)s2 + 2u);            // h0(s2+1) visible (usually already set)
        zclear();
        hgemm_glb(hbase(h0s, s2 + 1));              // next h0-part off the h1 chain
      }
    }
  }
}

extern "C" void kernel_launch(void* const* d_in, const int* in_sizes, int n_in,
                              void* d_out, int out_size, void* d_ws, size_t ws_size,
                              hipStream_t stream) {
  const float* x   = (const float*)d_in[0];
  const float* W0  = (const float*)d_in[1];
  const float* b0  = (const float*)d_in[2];
  const float* W1  = (const float*)d_in[3];
  const float* b1  = (const float*)d_in[4];
  const float* Wfc = (const float*)d_in[5];
  const float* bfc = (const float*)d_in[6];

  // ---- workspace: flags (4KB) | h rings (1MB) | wp0 (4MB) | wp1 (8MB) | xb (16.78MB) ----
  char* ws = (char*)d_ws;
  unsigned* flagsC = (unsigned*)ws;                   // 256 u32 (conversion epoch)
  unsigned* flagsA = (unsigned*)(ws + 1024);          // 64 u32 (h0 chain)
  unsigned* flagsB = (unsigned*)(ws + 2048);          // 64 u32 (h1 chain)
  size_t off = 4096;
  u64* h0s = (u64*)(ws + off); off += (size_t)NPAR * PARSTRIDE * 8;   // 512 KB
  u64* h1s = (u64*)(ws + off); off += (size_t)NPAR * PARSTRIDE * 8;   // 512 KB
  u64* wp0 = (u64*)(ws + off); off += (size_t)64 * 8 * 8 * 64 * 16;   // 4 MB
  u64* wp1 = (u64*)(ws + off); off += (size_t)64 * 8 * 16 * 64 * 16;  // 8 MB
  size_t need_wp = off;
  u64* xbu = (u64*)(ws + off); off += (size_t)TT * 64 * 64 * 16;      // 16.78 MB
  size_t need_xb = off;
  int use_wp = (ws_size >= need_wp) ? 1 : 0;
  int use_xb = (ws_size >= need_xb) ? 1 : 0;

  hipMemsetAsync(ws, 0, 4096, stream);                // zero all flag arrays

  lstm_persist<<<dim3(256), dim3(512), 0, stream>>>(
      x, W0, b0, W1, b1, Wfc, bfc, xbu, use_xb, wp0, wp1, use_wp,
      h0s, h1s, flagsC, flagsA, flagsB, (float*)d_out);
}

// Round 3
// 8577.859 us; speedup vs baseline: 1.4490x; 1.4405x over previous
//
#include <hip/hip_runtime.h>
#include <hip/hip_bf16.h>

typedef __attribute__((ext_vector_type(8))) short bf16x8;   // MFMA A/B frag (16B)
typedef __attribute__((ext_vector_type(4))) float f32x4;    // MFMA C/D frag
using bf16 = __hip_bfloat16;
typedef unsigned long long u64;

constexpr int BB = 64, TT = 256, DIN = 512, HH = 1024, DOUT = 512;
constexpr int P0 = 1544;       // LDS pitch for W0 rows (1536 + 8)
constexpr int P1 = 2056;       // LDS pitch for W1 rows (2048 + 8)
constexpr int HWORDS = 8192;   // one h half-array: 128 koct x 64 rows (u64)
constexpr int NW = 8;          // waves per block (2 per SIMD -> TLP)

#define MFMA16(a, b, c) __builtin_amdgcn_mfma_f32_16x16x32_bf16((a), (b), (c), 0, 0, 0)
#define ALOAD(p)  __hip_atomic_load((p),  __ATOMIC_RELAXED, __HIP_MEMORY_SCOPE_AGENT)
#define ASTORE(p, v) __hip_atomic_store((p), (v), __ATOMIC_RELAXED, __HIP_MEMORY_SCOPE_AGENT)

union frag_u { u64 q[2]; bf16x8 f; };

__device__ __forceinline__ short f2b(float f) {
  __hip_bfloat16 h = __float2bfloat16(f);           // RNE
  return *reinterpret_cast<short*>(&h);
}
__device__ __forceinline__ u64 pack4(float4 v) {
  return (u64)(unsigned short)f2b(v.x) | ((u64)(unsigned short)f2b(v.y) << 16) |
         ((u64)(unsigned short)f2b(v.z) << 32) | ((u64)(unsigned short)f2b(v.w) << 48);
}

// gate math: z -> (h bf16 bits), updates c register
__device__ __forceinline__ unsigned short gates(const float zv[4], const float br[4],
                                                float scale, float& cr, bool first) {
  float zf = (zv[0] + br[0]) * scale;
  float zi = (zv[1] + br[1]) * scale;
  float zo = (zv[2] + br[2]) * scale;
  float zg = (zv[3] + br[3]) * scale;
  float f = 1.0f / (1.0f + __expf(-zf));
  float i = 1.0f / (1.0f + __expf(-zi));
  float o = 1.0f / (1.0f + __expf(-zo));
  float g = tanhf(zg);
  float cn = f * (first ? 0.0f : cr) + i * g;
  cr = cn;
  __hip_bfloat16 hv = __float2bfloat16(o * tanhf(cn));
  return *reinterpret_cast<unsigned short*>(&hv);
}

// ---------------- persistent kernel: 256 blocks x 512 threads (8 waves), 1 block/CU --------
// Round-0 proven structure. ONE change: the per-step h gather (the measured bottleneck,
// 64MB/step through Infinity Cache at ~7.3TB/s = 8.8us/step) now uses PLAIN CACHED loads
// instead of agent-scope atomics. Coherence: bar_wait's post-poll fence is upgraded to
// AGENT scope, which emits buffer_inv (L1+L2 invalidate) on gfx950 — subsequent plain
// loads must miss to IC and see the freshly-published h, while 32 blocks/XCD then share
// the refill through their common L2 (256KB/XCD/step instead of 32x that from IC).
// Writer side unchanged: sc1 stores + s_waitcnt + flag are IC-visible before readers poll.
__global__ void __launch_bounds__(512, 1)
lstm_persist(const float* __restrict__ x,  const float* __restrict__ W0,
             const float* __restrict__ b0, const float* __restrict__ W1,
             const float* __restrict__ b1, const float* __restrict__ Wfc,
             const float* __restrict__ bfc,
             u64* __restrict__ xbu, int use_xb,
             u64* __restrict__ h0s, u64* __restrict__ h1s,
             unsigned* __restrict__ flagsA, unsigned* __restrict__ flagsB,
             float* __restrict__ out) {
  __shared__ unsigned short lw0[16 * P0];            // 49.4 KB  W0^T cols, bf16
  __shared__ unsigned short lw1[16 * P1];            // 65.8 KB  W1^T cols, bf16
  __shared__ float zbuf[NW][4][16][17];              // 34.8 KB  cross-wave z partials
  __shared__ unsigned short hs[64][4];               // 0.5 KB   h-tile staging

  const int tid  = threadIdx.x;
  const int wg   = blockIdx.x;
  const int lane = tid & 63;
  const int wv   = tid >> 6;          // wave id 0..7 = K-eighth
  const int n    = lane & 15;
  const int oct  = lane >> 4;
  const int mg   = tid & 63;          // epilogue row (tid<256 only)
  const int hq   = tid >> 6;          // epilogue hcol offset (tid<256 only)
  const float S0 = 1.0f / sqrtf((float)(DIN + HH));
  const float S1 = 1.0f / sqrtf((float)(HH + HH));

  float c0r = 0.0f, c1r = 0.0f;
  float b0r[4] = {0, 0, 0, 0}, b1r[4] = {0, 0, 0, 0};
  if (tid < 256) {
    const int hcol = wg * 4 + hq;
#pragma unroll
    for (int g = 0; g < 4; ++g) { b0r[g] = b0[g * HH + hcol]; b1r[g] = b1[g * HH + hcol]; }
  }

  // ---- stage this block's 16 columns of W0/W1 into LDS (fp32 -> bf16, transposed) ----
  {
    const int g = tid >> 7, kw = tid & 127;
    const int col0 = g * HH + wg * 4;
    for (int k = kw; k < DIN + HH; k += 128) {
      float4 u = *(const float4*)(W0 + (size_t)k * 4096 + col0);
      lw0[(g * 4 + 0) * P0 + k] = (unsigned short)f2b(u.x);
      lw0[(g * 4 + 1) * P0 + k] = (unsigned short)f2b(u.y);
      lw0[(g * 4 + 2) * P0 + k] = (unsigned short)f2b(u.z);
      lw0[(g * 4 + 3) * P0 + k] = (unsigned short)f2b(u.w);
    }
    for (int k = kw; k < 2 * HH; k += 128) {
      float4 u = *(const float4*)(W1 + (size_t)k * 4096 + col0);
      lw1[(g * 4 + 0) * P1 + k] = (unsigned short)f2b(u.x);
      lw1[(g * 4 + 1) * P1 + k] = (unsigned short)f2b(u.y);
      lw1[(g * 4 + 2) * P1 + k] = (unsigned short)f2b(u.z);
      lw1[(g * 4 + 3) * P1 + k] = (unsigned short)f2b(u.w);
    }
  }

  // ---- epoch 0: convert x -> bf16 split layout xb[t][koct 64][row 64] (16B units) ----
  if (use_xb) {
    const int t = wg;                 // block wg converts timestep wg
    for (int u = tid; u < 64 * 64; u += 512) {
      const int row = u & 63, ko = u >> 6;
      const float* p = x + ((size_t)row * TT + t) * DIN + ko * 8;
      float4 A = *(const float4*)p, B = *(const float4*)(p + 4);
      u64* d = xbu + ((size_t)(t * 64 + ko) * 64 + row) * 2;
      ASTORE(d, pack4(A));
      ASTORE(d + 1, pack4(B));
    }
  }
  __syncthreads();                    // drains conv stores (vmcnt 0 before barrier) + LDS staging

  f32x4 z0a[4], z1a[4];
  float zv[4] = {0, 0, 0, 0};

  auto flag_release = [&](unsigned* f, unsigned val) {
    if (tid < 64) __builtin_amdgcn_s_waitcnt(0);     // wave0: drain its sc1 stores
    if (tid == 0) ASTORE(f + wg, val);
  };
  auto bar_wait = [&](unsigned* f, unsigned target) {
    if (tid < 64) {                                  // wave 0 polls 4 flags/thread
      const u64* p = (const u64*)(f + tid * 4);
      for (;;) {
        u64 a = ALOAD(p), b = ALOAD(p + 1);
        if ((unsigned)a >= target && (unsigned)(a >> 32) >= target &&
            (unsigned)b >= target && (unsigned)(b >> 32) >= target) break;
        __builtin_amdgcn_s_sleep(1);
      }
    }
    __syncthreads();
    // AGENT-scope acquire: emits buffer_inv (L1+L2 invalidate) so the plain cached
    // h loads below cannot be served stale from this XCD's L2 (ring slots alias t-2).
    __builtin_amdgcn_fence(__ATOMIC_ACQUIRE, "agent");
  };

  flag_release(flagsA, 1u);           // x conversion published
  bar_wait(flagsA, 1u);

  // ---- x-part of layer0(t): 8 cached 16B loads + 8 MFMA per wave ----
  auto xpart = [&](int t) {
    if (use_xb) {
      const bf16* xb = (const bf16*)xbu;
#pragma unroll
      for (int s = 0; s < 2; ++s) {
        const int ko = wv * 8 + s * 4 + oct;
        bf16x8 bw = *(const bf16x8*)&lw0[n * P0 + ko * 8];
#pragma unroll
        for (int rt = 0; rt < 4; ++rt) {
          bf16x8 a = *(const bf16x8*)(xb + ((size_t)(t * 64 + ko) * 64 + rt * 16 + n) * 8);
          z0a[rt] = MFMA16(a, bw, z0a[rt]);
        }
      }
    } else {                          // fallback: fp32 x + on-the-fly cvt
#pragma unroll
      for (int s = 0; s < 2; ++s) {
        const int kp = wv * 64 + s * 32 + oct * 8;
        bf16x8 bw = *(const bf16x8*)&lw0[n * P0 + kp];
#pragma unroll
        for (int rt = 0; rt < 4; ++rt) {
          const float* p = x + ((size_t)(rt * 16 + n) * TT + t) * DIN + kp;
          float4 A = *(const float4*)p, B = *(const float4*)(p + 4);
          bf16x8 a;
          a[0] = f2b(A.x); a[1] = f2b(A.y); a[2] = f2b(A.z); a[3] = f2b(A.w);
          a[4] = f2b(B.x); a[5] = f2b(B.y); a[6] = f2b(B.z); a[7] = f2b(B.w);
          z0a[rt] = MFMA16(a, bw, z0a[rt]);
        }
      }
    }
  };

  // h0 dual-consume GEMM: z0 += h0*W0[512+k], z1 += h0*W1[k]  (16 frags/wave)
  // h loads are PLAIN cached loads (L2-shared across the XCD); bar_wait's agent
  // acquire fence guarantees freshness.
  auto h0gemm = [&](const u64* h0b) {
    u64 lo[16], hi[16];
#pragma unroll
    for (int i = 0; i < 16; ++i) {
      const int s = i >> 2, rt = i & 3;
      const int idx = (wv * 16 + s * 4 + oct) * 64 + rt * 16 + n;
      lo[i] = h0b[idx];
      hi[i] = h0b[HWORDS + idx];
    }
#pragma unroll
    for (int s = 0; s < 4; ++s) {
      const int kp = wv * 128 + s * 32 + oct * 8;
      bf16x8 bw0 = *(const bf16x8*)&lw0[n * P0 + 512 + kp];
      bf16x8 bw1 = *(const bf16x8*)&lw1[n * P1 + kp];
#pragma unroll
      for (int rt = 0; rt < 4; ++rt) {
        frag_u u; u.q[0] = lo[s * 4 + rt]; u.q[1] = hi[s * 4 + rt];
        z0a[rt] = MFMA16(u.f, bw0, z0a[rt]);
        z1a[rt] = MFMA16(u.f, bw1, z1a[rt]);
      }
    }
  };
  // z1 += h * W1[koff + k]
  auto h1gemm = [&](const u64* hb, int koff) {
    u64 lo[16], hi[16];
#pragma unroll
    for (int i = 0; i < 16; ++i) {
      const int s = i >> 2, rt = i & 3;
      const int idx = (wv * 16 + s * 4 + oct) * 64 + rt * 16 + n;
      lo[i] = hb[idx];
      hi[i] = hb[HWORDS + idx];
    }
#pragma unroll
    for (int s = 0; s < 4; ++s) {
      const int kp = wv * 128 + s * 32 + oct * 8;
      bf16x8 bw = *(const bf16x8*)&lw1[n * P1 + koff + kp];
#pragma unroll
      for (int rt = 0; rt < 4; ++rt) {
        frag_u u; u.q[0] = lo[s * 4 + rt]; u.q[1] = hi[s * 4 + rt];
        z1a[rt] = MFMA16(u.f, bw, z1a[rt]);
      }
    }
  };

  auto publish = [&](u64* dst) {
    if (tid < 64) {
      u64 val = *(const u64*)&hs[tid][0];
      ASTORE(dst + (size_t)(wg & 1) * HWORDS + (wg >> 1) * 64 + tid, val);
    }
  };
  auto zreduce = [&](f32x4 za[4]) {
#pragma unroll
    for (int rt = 0; rt < 4; ++rt)
#pragma unroll
      for (int r = 0; r < 4; ++r) zbuf[wv][rt][oct * 4 + r][n] = za[rt][r];
    __syncthreads();
    if (tid < 256) {
#pragma unroll
      for (int g = 0; g < 4; ++g) {
        float s = 0.f;
#pragma unroll
        for (int w = 0; w < NW; ++w) s += zbuf[w][mg >> 4][mg & 15][g * 4 + hq];
        zv[g] = s;
      }
    }
  };

  // =================== window 0: layer0(0), x-part only ===================
#pragma unroll
  for (int rt = 0; rt < 4; ++rt) z0a[rt] = (f32x4){0.f, 0.f, 0.f, 0.f};
  xpart(0);
  zreduce(z0a);
  if (tid < 256) hs[mg][hq] = gates(zv, b0r, S0, c0r, true);
  __syncthreads();
  publish(h0s);                       // h0(0), parity 0
  flag_release(flagsA, 2u);
  flag_release(flagsB, 1u);           // vacuous
#pragma unroll
  for (int rt = 0; rt < 4; ++rt) z0a[rt] = (f32x4){0.f, 0.f, 0.f, 0.f};
  xpart(1);

  // =================== windows 1..255 ===================
  for (int t = 1; t < TT; ++t) {
    bar_wait(flagsA, (unsigned)t + 1u);             // h0(t-1) visible
    const u64* h0b = h0s + (size_t)(((t - 1) & 1) * 2) * HWORDS;
#pragma unroll
    for (int rt = 0; rt < 4; ++rt) z1a[rt] = (f32x4){0.f, 0.f, 0.f, 0.f};
    h0gemm(h0b);

    zreduce(z0a);                                   // z0 complete
    if (tid < 256) hs[mg][hq] = gates(zv, b0r, S0, c0r, false);
    __syncthreads();
    publish(h0s + (size_t)((t & 1) * 2) * HWORDS);  // h0(t)
    flag_release(flagsA, (unsigned)t + 2u);         // release h0 chain EARLY

    if (t < TT - 1) {                               // overlap x(t+1)
#pragma unroll
      for (int rt = 0; rt < 4; ++rt) z0a[rt] = (f32x4){0.f, 0.f, 0.f, 0.f};
      xpart(t + 1);
    }

    if (t >= 2) {
      bar_wait(flagsB, (unsigned)t);                // h1(t-2) visible
      h1gemm(h1s + (size_t)((t & 1) * 2) * HWORDS, 1024);
    }
    zreduce(z1a);
    if (tid < 256) hs[mg][hq] = gates(zv, b1r, S1, c1r, t == 1);
    __syncthreads();
    publish(h1s + (size_t)(((t - 1) & 1) * 2) * HWORDS);  // h1(t-1)
    flag_release(flagsB, (unsigned)t + 1u);
  }

  // =================== final window: layer1(255) ===================
  {
    bar_wait(flagsA, 257u);                         // h0(255), parity 1
#pragma unroll
    for (int rt = 0; rt < 4; ++rt) z1a[rt] = (f32x4){0.f, 0.f, 0.f, 0.f};
    h1gemm(h0s + 2 * HWORDS, 0);                    // z1 += h0(255) * W1lo
    bar_wait(flagsB, 256u);                         // h1(254), parity 0
    h1gemm(h1s, 1024);                              // z1 += h1(254) * W1hi
    zreduce(z1a);
    if (tid < 256) hs[mg][hq] = gates(zv, b1r, S1, c1r, false);
    __syncthreads();
    publish(h1s + 2 * HWORDS);                      // h1(255), parity 1
    flag_release(flagsB, 257u);
  }

  // ============ final FC: out = h1(255) @ Wfc + bfc (blocks 0..31) ============
  if (wg < DOUT / 16) {
    bar_wait(flagsB, 257u);                         // agent acquire -> fresh h1(255)
    {  // stage Wfc cols [wg*16, wg*16+16) into lw0 region (fp32 -> bf16)
      const int q = tid >> 7, kw = tid & 127;
      for (int k = kw; k < HH; k += 128) {
        float4 u = *(const float4*)(Wfc + (size_t)k * DOUT + wg * 16 + q * 4);
        lw0[(q * 4 + 0) * P0 + k] = (unsigned short)f2b(u.x);
        lw0[(q * 4 + 1) * P0 + k] = (unsigned short)f2b(u.y);
        lw0[(q * 4 + 2) * P0 + k] = (unsigned short)f2b(u.z);
        lw0[(q * 4 + 3) * P0 + k] = (unsigned short)f2b(u.w);
      }
    }
    __syncthreads();
    if (tid < 256) {
      const int v4 = tid >> 6;                      // 0..3 (waves 0-3 do the FC)
      const u64* hb = h1s + 2 * HWORDS;             // h1(255)
      f32x4 acc0 = {0.f, 0.f, 0.f, 0.f}, acc1 = {0.f, 0.f, 0.f, 0.f};
#pragma unroll
      for (int it = 0; it < 16; ++it) {
        const int idxA = (it * 8 + oct) * 64 + v4 * 16 + n;
        const int idxB = (it * 8 + 4 + oct) * 64 + v4 * 16 + n;
        frag_u uA, uB;
        uA.q[0] = hb[idxA]; uA.q[1] = hb[HWORDS + idxA];
        uB.q[0] = hb[idxB]; uB.q[1] = hb[HWORDS + idxB];
        bf16x8 bwA = *(const bf16x8*)&lw0[n * P0 + it * 64 + oct * 8];
        bf16x8 bwB = *(const bf16x8*)&lw0[n * P0 + it * 64 + 32 + oct * 8];
        acc0 = MFMA16(uA.f, bwA, acc0);
        acc1 = MFMA16(uB.f, bwB, acc1);
      }
      float bb = bfc[wg * 16 + n];
#pragma unroll
      for (int r = 0; r < 4; ++r) {
        int row = v4 * 16 + oct * 4 + r;
        out[(size_t)row * DOUT + wg * 16 + n] = acc0[r] + acc1[r] + bb;
      }
    }
  }
}

extern "C" void kernel_launch(void* const* d_in, const int* in_sizes, int n_in,
                              void* d_out, int out_size, void* d_ws, size_t ws_size,
                              hipStream_t stream) {
  const float* x   = (const float*)d_in[0];
  const float* W0  = (const float*)d_in[1];
  const float* b0  = (const float*)d_in[2];
  const float* W1  = (const float*)d_in[3];
  const float* b1  = (const float*)d_in[4];
  const float* Wfc = (const float*)d_in[5];
  const float* bfc = (const float*)d_in[6];

  // ---- workspace: flags (4KB) + h buffers (512KB) + xb (16.78MB) ----
  char* ws = (char*)d_ws;
  unsigned* flagsA = (unsigned*)ws;                   // 256 u32
  unsigned* flagsB = (unsigned*)(ws + 1024);          // 256 u32
  u64* h0s = (u64*)(ws + 4096);                       // 4*HWORDS u64 = 256 KB
  u64* h1s = h0s + 4 * HWORDS;                        // 256 KB
  u64* xbu = h1s + 4 * HWORDS;                        // 256*64*64 units * 16B = 16.78 MB
  size_t needed = 4096 + 2 * 4 * (size_t)HWORDS * 8 + (size_t)TT * 64 * 64 * 16;
  int use_xb = (ws_size >= needed) ? 1 : 0;

  hipMemsetAsync(ws, 0, 4096, stream);                // zero both flag arrays

  lstm_persist<<<dim3(256), dim3(512), 0, stream>>>(
      x, W0, b0, W1, b1, Wfc, bfc, xbu, use_xb, h0s, h1s, flagsA, flagsB, (float*)d_out);
}

// Round 4
// 2146.092 us; speedup vs baseline: 5.7916x; 3.9970x over previous
//
#include <hip/hip_runtime.h>
#include <hip/hip_bf16.h>

typedef __attribute__((ext_vector_type(8))) short bf16x8;   // MFMA A/B frag (16B)
typedef __attribute__((ext_vector_type(4))) float f32x4;    // MFMA C/D frag
using bf16 = __hip_bfloat16;
typedef unsigned long long u64;

constexpr int BB = 64, TT = 256, DIN = 512, HH = 1024, DOUT = 512;
constexpr int P0 = 1544;       // LDS pitch for W0 rows (1536 + 8)
constexpr int P1 = 2056;       // LDS pitch for W1 rows (2048 + 8)
constexpr int HWORDS = 8192;   // one h half-array: 128 koct x 64 rows (u64)
constexpr int PARSTRIDE = 2 * HWORDS;  // u64 per h slot (lo+hi) = 128 KB
constexpr int NW = 8;          // waves per block (2 per SIMD -> TLP)

#define MFMA16(a, b, c) __builtin_amdgcn_mfma_f32_16x16x32_bf16((a), (b), (c), 0, 0, 0)
#define ALOAD(p)  __hip_atomic_load((p),  __ATOMIC_RELAXED, __HIP_MEMORY_SCOPE_AGENT)
#define ASTORE(p, v) __hip_atomic_store((p), (v), __ATOMIC_RELAXED, __HIP_MEMORY_SCOPE_AGENT)

union frag_u { u64 q[2]; bf16x8 f; };

__device__ __forceinline__ short f2b(float f) {
  __hip_bfloat16 h = __float2bfloat16(f);           // RNE
  return *reinterpret_cast<short*>(&h);
}
__device__ __forceinline__ u64 pack4(float4 v) {
  return (u64)(unsigned short)f2b(v.x) | ((u64)(unsigned short)f2b(v.y) << 16) |
         ((u64)(unsigned short)f2b(v.z) << 32) | ((u64)(unsigned short)f2b(v.w) << 48);
}

// gate math: z -> (h bf16 bits), updates c register
__device__ __forceinline__ unsigned short gates(const float zv[4], const float br[4],
                                                float scale, float& cr, bool first) {
  float zf = (zv[0] + br[0]) * scale;
  float zi = (zv[1] + br[1]) * scale;
  float zo = (zv[2] + br[2]) * scale;
  float zg = (zv[3] + br[3]) * scale;
  float f = 1.0f / (1.0f + __expf(-zf));
  float i = 1.0f / (1.0f + __expf(-zi));
  float o = 1.0f / (1.0f + __expf(-zo));
  float g = tanhf(zg);
  float cn = f * (first ? 0.0f : cr) + i * g;
  cr = cn;
  __hip_bfloat16 hv = __float2bfloat16(o * tanhf(cn));
  return *reinterpret_cast<unsigned short*>(&hv);
}

// ---------------- persistent kernel: 256 blocks x 512 threads (8 waves), 1 block/CU --------
// Round-0 proven structure + FRESH-ADDRESS h publication (round-4 change):
// every timestep publishes h0(t)/h1(t) to a brand-new 128KB slot (sc1 stores, IC-visible
// before the flag). Readers use PLAIN CACHED loads: since each address is written exactly
// once, a reader's L2 can only miss-to-IC (fresh) — staleness is impossible without
// address reuse, so NO invalidating fence is needed (round-3 lesson: buffer_inv per
// barrier is catastrophic). 32 blocks/XCD then share one L2 refill per slot: the h
// all-gather drops from 64MB/step served by IC (round-0 bottleneck, ~7us/step) to
// ~2MB/step from IC + L2-bandwidth fanout. Pattern identical to the already-proven xb
// convert-once/read-cached scheme. Ring+ALOAD fallback if workspace < 68MB.
__global__ void __launch_bounds__(512, 1)
lstm_persist(const float* __restrict__ x,  const float* __restrict__ W0,
             const float* __restrict__ b0, const float* __restrict__ W1,
             const float* __restrict__ b1, const float* __restrict__ Wfc,
             const float* __restrict__ bfc,
             u64* __restrict__ xbu, int use_xb, int use_fresh,
             u64* __restrict__ h0s, u64* __restrict__ h1s,
             unsigned* __restrict__ flagsA, unsigned* __restrict__ flagsB,
             float* __restrict__ out) {
  __shared__ unsigned short lw0[16 * P0];            // 49.4 KB  W0^T cols, bf16
  __shared__ unsigned short lw1[16 * P1];            // 65.8 KB  W1^T cols, bf16
  __shared__ float zbuf[NW][4][16][17];              // 34.8 KB  cross-wave z partials
  __shared__ unsigned short hs[64][4];               // 0.5 KB   h-tile staging

  const int tid  = threadIdx.x;
  const int wg   = blockIdx.x;
  const int lane = tid & 63;
  const int wv   = tid >> 6;          // wave id 0..7 = K-eighth
  const int n    = lane & 15;
  const int oct  = lane >> 4;
  const int mg   = tid & 63;          // epilogue row (tid<256 only)
  const int hq   = tid >> 6;          // epilogue hcol offset (tid<256 only)
  const float S0 = 1.0f / sqrtf((float)(DIN + HH));
  const float S1 = 1.0f / sqrtf((float)(HH + HH));

  float c0r = 0.0f, c1r = 0.0f;
  float b0r[4] = {0, 0, 0, 0}, b1r[4] = {0, 0, 0, 0};
  if (tid < 256) {
    const int hcol = wg * 4 + hq;
#pragma unroll
    for (int g = 0; g < 4; ++g) { b0r[g] = b0[g * HH + hcol]; b1r[g] = b1[g * HH + hcol]; }
  }

  // ---- stage this block's 16 columns of W0/W1 into LDS (fp32 -> bf16, transposed) ----
  {
    const int g = tid >> 7, kw = tid & 127;
    const int col0 = g * HH + wg * 4;
    for (int k = kw; k < DIN + HH; k += 128) {
      float4 u = *(const float4*)(W0 + (size_t)k * 4096 + col0);
      lw0[(g * 4 + 0) * P0 + k] = (unsigned short)f2b(u.x);
      lw0[(g * 4 + 1) * P0 + k] = (unsigned short)f2b(u.y);
      lw0[(g * 4 + 2) * P0 + k] = (unsigned short)f2b(u.z);
      lw0[(g * 4 + 3) * P0 + k] = (unsigned short)f2b(u.w);
    }
    for (int k = kw; k < 2 * HH; k += 128) {
      float4 u = *(const float4*)(W1 + (size_t)k * 4096 + col0);
      lw1[(g * 4 + 0) * P1 + k] = (unsigned short)f2b(u.x);
      lw1[(g * 4 + 1) * P1 + k] = (unsigned short)f2b(u.y);
      lw1[(g * 4 + 2) * P1 + k] = (unsigned short)f2b(u.z);
      lw1[(g * 4 + 3) * P1 + k] = (unsigned short)f2b(u.w);
    }
  }

  // ---- epoch 0: convert x -> bf16 split layout xb[t][koct 64][row 64] (16B units) ----
  if (use_xb) {
    const int t = wg;                 // block wg converts timestep wg
    for (int u = tid; u < 64 * 64; u += 512) {
      const int row = u & 63, ko = u >> 6;
      const float* p = x + ((size_t)row * TT + t) * DIN + ko * 8;
      float4 A = *(const float4*)p, B = *(const float4*)(p + 4);
      u64* d = xbu + ((size_t)(t * 64 + ko) * 64 + row) * 2;
      ASTORE(d, pack4(A));
      ASTORE(d + 1, pack4(B));
    }
  }
  __syncthreads();                    // drains conv stores (vmcnt 0 before barrier) + LDS staging

  f32x4 z0a[4], z1a[4];
  float zv[4] = {0, 0, 0, 0};

  auto flag_release = [&](unsigned* f, unsigned val) {
    if (tid < 64) __builtin_amdgcn_s_waitcnt(0);     // wave0: drain its sc1 stores
    if (tid == 0) ASTORE(f + wg, val);
  };
  auto bar_wait = [&](unsigned* f, unsigned target) {
    if (tid < 64) {                                  // wave 0 polls 4 flags/thread
      const u64* p = (const u64*)(f + tid * 4);
      for (;;) {
        u64 a = ALOAD(p), b = ALOAD(p + 1);
        if ((unsigned)a >= target && (unsigned)(a >> 32) >= target &&
            (unsigned)b >= target && (unsigned)(b >> 32) >= target) break;
        __builtin_amdgcn_s_sleep(1);
      }
    }
    __syncthreads();
    __builtin_amdgcn_fence(__ATOMIC_ACQUIRE, "workgroup");   // ordering only (no invalidate)
  };
  // h slot for timestep t: fresh mode = unique slot per step (plain-load coherent);
  // ring mode = round-0 parity ring (requires ALOAD on read).
  auto hslot = [&](u64* arr, int t) -> u64* {
    return arr + (size_t)(use_fresh ? t : (t & 1)) * PARSTRIDE;
  };

  flag_release(flagsA, 1u);           // x conversion published
  bar_wait(flagsA, 1u);

  // ---- x-part of layer0(t): 8 cached 16B loads + 8 MFMA per wave ----
  auto xpart = [&](int t) {
    if (use_xb) {
      const bf16* xb = (const bf16*)xbu;
#pragma unroll
      for (int s = 0; s < 2; ++s) {
        const int ko = wv * 8 + s * 4 + oct;
        bf16x8 bw = *(const bf16x8*)&lw0[n * P0 + ko * 8];
#pragma unroll
        for (int rt = 0; rt < 4; ++rt) {
          bf16x8 a = *(const bf16x8*)(xb + ((size_t)(t * 64 + ko) * 64 + rt * 16 + n) * 8);
          z0a[rt] = MFMA16(a, bw, z0a[rt]);
        }
      }
    } else {                          // fallback: fp32 x + on-the-fly cvt
#pragma unroll
      for (int s = 0; s < 2; ++s) {
        const int kp = wv * 64 + s * 32 + oct * 8;
        bf16x8 bw = *(const bf16x8*)&lw0[n * P0 + kp];
#pragma unroll
        for (int rt = 0; rt < 4; ++rt) {
          const float* p = x + ((size_t)(rt * 16 + n) * TT + t) * DIN + kp;
          float4 A = *(const float4*)p, B = *(const float4*)(p + 4);
          bf16x8 a;
          a[0] = f2b(A.x); a[1] = f2b(A.y); a[2] = f2b(A.z); a[3] = f2b(A.w);
          a[4] = f2b(B.x); a[5] = f2b(B.y); a[6] = f2b(B.z); a[7] = f2b(B.w);
          z0a[rt] = MFMA16(a, bw, z0a[rt]);
        }
      }
    }
  };

  // h frag loads: plain cached (fresh slots, L2-shared across XCD) or ALOAD (ring).
  auto hload = [&](const u64* hb, u64 lo[16], u64 hi[16]) {
    if (use_fresh) {
#pragma unroll
      for (int i = 0; i < 16; ++i) {
        const int s = i >> 2, rt = i & 3;
        const int idx = (wv * 16 + s * 4 + oct) * 64 + rt * 16 + n;
        lo[i] = hb[idx];
        hi[i] = hb[HWORDS + idx];
      }
    } else {
#pragma unroll
      for (int i = 0; i < 16; ++i) {
        const int s = i >> 2, rt = i & 3;
        const int idx = (wv * 16 + s * 4 + oct) * 64 + rt * 16 + n;
        lo[i] = ALOAD(hb + idx);
        hi[i] = ALOAD(hb + HWORDS + idx);
      }
    }
  };

  // h0 dual-consume GEMM: z0 += h0*W0[512+k], z1 += h0*W1[k]  (16 frags/wave)
  auto h0gemm = [&](const u64* h0b) {
    u64 lo[16], hi[16];
    hload(h0b, lo, hi);
#pragma unroll
    for (int s = 0; s < 4; ++s) {
      const int kp = wv * 128 + s * 32 + oct * 8;
      bf16x8 bw0 = *(const bf16x8*)&lw0[n * P0 + 512 + kp];
      bf16x8 bw1 = *(const bf16x8*)&lw1[n * P1 + kp];
#pragma unroll
      for (int rt = 0; rt < 4; ++rt) {
        frag_u u; u.q[0] = lo[s * 4 + rt]; u.q[1] = hi[s * 4 + rt];
        z0a[rt] = MFMA16(u.f, bw0, z0a[rt]);
        z1a[rt] = MFMA16(u.f, bw1, z1a[rt]);
      }
    }
  };
  // z1 += h * W1[koff + k]
  auto h1gemm = [&](const u64* hb, int koff) {
    u64 lo[16], hi[16];
    hload(hb, lo, hi);
#pragma unroll
    for (int s = 0; s < 4; ++s) {
      const int kp = wv * 128 + s * 32 + oct * 8;
      bf16x8 bw = *(const bf16x8*)&lw1[n * P1 + koff + kp];
#pragma unroll
      for (int rt = 0; rt < 4; ++rt) {
        frag_u u; u.q[0] = lo[s * 4 + rt]; u.q[1] = hi[s * 4 + rt];
        z1a[rt] = MFMA16(u.f, bw, z1a[rt]);
      }
    }
  };

  auto publish = [&](u64* dst) {                     // dst = slot base
    if (tid < 64) {
      u64 val = *(const u64*)&hs[tid][0];
      ASTORE(dst + (size_t)(wg & 1) * HWORDS + (wg >> 1) * 64 + tid, val);
    }
  };
  auto zreduce = [&](f32x4 za[4]) {
#pragma unroll
    for (int rt = 0; rt < 4; ++rt)
#pragma unroll
      for (int r = 0; r < 4; ++r) zbuf[wv][rt][oct * 4 + r][n] = za[rt][r];
    __syncthreads();
    if (tid < 256) {
#pragma unroll
      for (int g = 0; g < 4; ++g) {
        float s = 0.f;
#pragma unroll
        for (int w = 0; w < NW; ++w) s += zbuf[w][mg >> 4][mg & 15][g * 4 + hq];
        zv[g] = s;
      }
    }
  };

  // =================== window 0: layer0(0), x-part only ===================
#pragma unroll
  for (int rt = 0; rt < 4; ++rt) z0a[rt] = (f32x4){0.f, 0.f, 0.f, 0.f};
  xpart(0);
  zreduce(z0a);
  if (tid < 256) hs[mg][hq] = gates(zv, b0r, S0, c0r, true);
  __syncthreads();
  publish(hslot(h0s, 0));             // h0(0)
  flag_release(flagsA, 2u);
  flag_release(flagsB, 1u);           // vacuous
#pragma unroll
  for (int rt = 0; rt < 4; ++rt) z0a[rt] = (f32x4){0.f, 0.f, 0.f, 0.f};
  xpart(1);

  // =================== windows 1..255 ===================
  for (int t = 1; t < TT; ++t) {
    bar_wait(flagsA, (unsigned)t + 1u);             // h0(t-1) visible
#pragma unroll
    for (int rt = 0; rt < 4; ++rt) z1a[rt] = (f32x4){0.f, 0.f, 0.f, 0.f};
    h0gemm(hslot(h0s, t - 1));

    zreduce(z0a);                                   // z0 complete
    if (tid < 256) hs[mg][hq] = gates(zv, b0r, S0, c0r, false);
    __syncthreads();
    publish(hslot(h0s, t));                         // h0(t)
    flag_release(flagsA, (unsigned)t + 2u);         // release h0 chain EARLY

    if (t < TT - 1) {                               // overlap x(t+1)
#pragma unroll
      for (int rt = 0; rt < 4; ++rt) z0a[rt] = (f32x4){0.f, 0.f, 0.f, 0.f};
      xpart(t + 1);
    }

    if (t >= 2) {
      bar_wait(flagsB, (unsigned)t);                // h1(t-2) visible
      h1gemm(hslot(h1s, t - 2), 1024);
    }
    zreduce(z1a);
    if (tid < 256) hs[mg][hq] = gates(zv, b1r, S1, c1r, t == 1);
    __syncthreads();
    publish(hslot(h1s, t - 1));                     // h1(t-1)
    flag_release(flagsB, (unsigned)t + 1u);
  }

  // =================== final window: layer1(255) ===================
  {
    bar_wait(flagsA, 257u);                         // h0(255)
#pragma unroll
    for (int rt = 0; rt < 4; ++rt) z1a[rt] = (f32x4){0.f, 0.f, 0.f, 0.f};
    h1gemm(hslot(h0s, 255), 0);                     // z1 += h0(255) * W1lo
    bar_wait(flagsB, 256u);                         // h1(254) visible
    h1gemm(hslot(h1s, 254), 1024);                  // z1 += h1(254) * W1hi
    zreduce(z1a);
    if (tid < 256) hs[mg][hq] = gates(zv, b1r, S1, c1r, false);
    __syncthreads();
    publish(hslot(h1s, 255));                       // h1(255)
    flag_release(flagsB, 257u);
  }

  // ============ final FC: out = h1(255) @ Wfc + bfc (blocks 0..31) ============
  if (wg < DOUT / 16) {
    bar_wait(flagsB, 257u);
    {  // stage Wfc cols [wg*16, wg*16+16) into lw0 region (fp32 -> bf16)
      const int q = tid >> 7, kw = tid & 127;
      for (int k = kw; k < HH; k += 128) {
        float4 u = *(const float4*)(Wfc + (size_t)k * DOUT + wg * 16 + q * 4);
        lw0[(q * 4 + 0) * P0 + k] = (unsigned short)f2b(u.x);
        lw0[(q * 4 + 1) * P0 + k] = (unsigned short)f2b(u.y);
        lw0[(q * 4 + 2) * P0 + k] = (unsigned short)f2b(u.z);
        lw0[(q * 4 + 3) * P0 + k] = (unsigned short)f2b(u.w);
      }
    }
    __syncthreads();
    if (tid < 256) {
      const int v4 = tid >> 6;                      // 0..3 (waves 0-3 do the FC)
      const u64* hb = hslot(h1s, 255);              // h1(255)
      f32x4 acc0 = {0.f, 0.f, 0.f, 0.f}, acc1 = {0.f, 0.f, 0.f, 0.f};
#pragma unroll
      for (int it = 0; it < 16; ++it) {
        const int idxA = (it * 8 + oct) * 64 + v4 * 16 + n;
        const int idxB = (it * 8 + 4 + oct) * 64 + v4 * 16 + n;
        frag_u uA, uB;
        if (use_fresh) {
          uA.q[0] = hb[idxA]; uA.q[1] = hb[HWORDS + idxA];
          uB.q[0] = hb[idxB]; uB.q[1] = hb[HWORDS + idxB];
        } else {
          uA.q[0] = ALOAD(hb + idxA); uA.q[1] = ALOAD(hb + HWORDS + idxA);
          uB.q[0] = ALOAD(hb + idxB); uB.q[1] = ALOAD(hb + HWORDS + idxB);
        }
        bf16x8 bwA = *(const bf16x8*)&lw0[n * P0 + it * 64 + oct * 8];
        bf16x8 bwB = *(const bf16x8*)&lw0[n * P0 + it * 64 + 32 + oct * 8];
        acc0 = MFMA16(uA.f, bwA, acc0);
        acc1 = MFMA16(uB.f, bwB, acc1);
      }
      float bb = bfc[wg * 16 + n];
#pragma unroll
      for (int r = 0; r < 4; ++r) {
        int row = v4 * 16 + oct * 4 + r;
        out[(size_t)row * DOUT + wg * 16 + n] = acc0[r] + acc1[r] + bb;
      }
    }
  }
}

extern "C" void kernel_launch(void* const* d_in, const int* in_sizes, int n_in,
                              void* d_out, int out_size, void* d_ws, size_t ws_size,
                              hipStream_t stream) {
  const float* x   = (const float*)d_in[0];
  const float* W0  = (const float*)d_in[1];
  const float* b0  = (const float*)d_in[2];
  const float* W1  = (const float*)d_in[3];
  const float* b1  = (const float*)d_in[4];
  const float* Wfc = (const float*)d_in[5];
  const float* bfc = (const float*)d_in[6];

  char* ws = (char*)d_ws;
  unsigned* flagsA = (unsigned*)ws;                   // 256 u32
  unsigned* flagsB = (unsigned*)(ws + 1024);          // 256 u32

  const size_t slotB  = (size_t)PARSTRIDE * 8;        // 128 KB per h slot
  const size_t xbB    = (size_t)TT * 64 * 64 * 16;    // 16.78 MB
  const size_t needF  = 4096 + 2 * (size_t)TT * slotB;          // fresh: 64 MB + flags
  const size_t needFX = needF + xbB;                            // + xb
  const size_t needR  = 4096 + 2 * 2 * slotB;                   // ring: 512 KB + flags
  const size_t needRX = needR + xbB;

  int use_fresh, use_xb;
  u64 *h0s, *h1s, *xbu;
  if (ws_size >= needF) {                             // fresh-address mode
    use_fresh = 1;
    h0s = (u64*)(ws + 4096);                          // 256 slots x 128 KB = 32 MB
    h1s = h0s + (size_t)TT * PARSTRIDE;               // 32 MB
    xbu = h1s + (size_t)TT * PARSTRIDE;               // 16.78 MB (if it fits)
    use_xb = (ws_size >= needFX) ? 1 : 0;
  } else {                                            // round-0 ring mode (ALOAD)
    use_fresh = 0;
    h0s = (u64*)(ws + 4096);                          // 2 slots x 128 KB
    h1s = h0s + 2 * PARSTRIDE;
    xbu = h1s + 2 * PARSTRIDE;
    use_xb = (ws_size >= needRX) ? 1 : 0;
  }

  hipMemsetAsync(ws, 0, 4096, stream);                // zero both flag arrays

  lstm_persist<<<dim3(256), dim3(512), 0, stream>>>(
      x, W0, b0, W1, b1, Wfc, bfc, xbu, use_xb, use_fresh,
      h0s, h1s, flagsA, flagsB, (float*)d_out);
}